// Round 17
// baseline (84.323 us; speedup 1.0000x reference)
//
#include <hip/hip_runtime.h>
#include <cstdint>

static constexpr int T1   = 512;    // fused kernel block size (8 waves)
static constexpr int T2   = 256;    // reduce kernel block size
static constexpr int BS   = 4096;
static constexpr int C    = 16384;
static constexpr int D    = 128;
static constexpr int HALF = 2048;   // rows 0..2047 pair with rows 2048..4095
static constexpr int NPOS = 4;
static constexpr int NNEG = 20;
static constexpr int NSEL = 24;
static constexpr int QPT1 = 8;      // int4 quads per thread per row (32 cols)
static constexpr int CAPN = 256;    // per-row candidate capacity (mean 128, +11sigma)

// Pre-filter threshold: top 1/128 of u32 -> ~128 candidates/row (need >=20
// negatives; P(shortfall) ~ e^-45). Compaction is LOSSLESS above TH, so
// selection is exact with no rebuild path.
static constexpr uint32_t TH = 0xFE000000u;

__device__ __forceinline__ uint32_t rotl32(uint32_t x, int r) {
  return __builtin_amdgcn_alignbit(x, x, 32 - r);   // 1 instr
}

__device__ __forceinline__ int mbcnt64(uint64_t m) {   // popc(mask & lt_lane)
  return (int)__builtin_amdgcn_mbcnt_hi((uint32_t)(m >> 32),
             __builtin_amdgcn_mbcnt_lo((uint32_t)m, 0u));
}

static constexpr uint32_t KS1 = 42u;
static constexpr uint32_t KS2 = 0x1BD11BDAu ^ 42u;   // ks0 = 0

// ---- JAX threefry2x32 (20 rounds), key = PRNGKey(42) = [0, 42] ----
// 8 independent chains, round-interleaved (ILP=8). Chains 0-3: quad j
// (counter n0+k), chains 4-7: quad j+1 (n1 = n0 + 2048).
// Mid-stream key injections are FOLDED into the next round's add:
//   x1 += a1; x0 = x0 + a0 + x1 (v_add3)  — saves 1 op/chain/injection.
__device__ __forceinline__ void tf8(uint32_t n0, uint32_t n1,
                                    uint32_t (&oa)[8], uint32_t (&ob)[8]) {
  uint32_t x0[8], x1[8];
#pragma unroll
  for (int k = 0; k < 8; ++k) {
    const uint32_t n = (k < 4) ? (n0 + k) : (n1 + (k - 4));
    x0[k] = n; x1[k] = n + (0x2000000u + KS1);
  }
#define R8(r) { _Pragma("unroll") \
  for (int k = 0; k < 8; ++k) { x0[k] += x1[k]; x1[k] = rotl32(x1[k], (r)); x1[k] ^= x0[k]; } }
// folded injection + first round of next group
#define FR8(a0, a1, r) { _Pragma("unroll") \
  for (int k = 0; k < 8; ++k) { x1[k] += (a1); x0[k] = x0[k] + (a0) + x1[k]; \
                                x1[k] = rotl32(x1[k], (r)); x1[k] ^= x0[k]; } }
  R8(13) R8(15) R8(26) R8(6)
  FR8(KS1, KS2 + 1u, 17) R8(29) R8(16) R8(24)
  FR8(KS2, 2u, 13)       R8(15) R8(26) R8(6)
  FR8(0u, KS1 + 3u, 17)  R8(29) R8(16) R8(24)
  FR8(KS1, KS2 + 4u, 13) R8(15) R8(26) R8(6)
#undef R8
#undef FR8
#pragma unroll
  for (int k = 0; k < 8; ++k) { oa[k] = x0[k] + KS2; ob[k] = x1[k] + 5u; }
}

// ---- fused kernel: labels + hash + compaction + set-select + sim + BCE ----
// comp32 for o >= TH: ((o & ~0x1FF) << 5) + KeAdj  ==  ((o-TH)>>9)<<14 + Ke
// (mod 2^32; KeAdj = Ke + 0x40000000, Ke = 32767-col). Low 14 bits = 16383-col
// (col recovery); comps distinct per row; larger = better, ties -> smaller col
// (matches jax top_k). comp < 2^31.
__global__ __launch_bounds__(T1) void supcon_fused(
    const float* __restrict__ feat, const float* __restrict__ proto,
    const int* __restrict__ lab, float* __restrict__ row_ws) {
  __shared__ uint32_t candArr[2][CAPN];
  __shared__ int candCnt[2];
  __shared__ int selL[NSEL], selH[NSEL];
  __shared__ int posCnt[2];
  __shared__ int posBuf[2][4];
  __shared__ float ffL[D], ffH[D];
  __shared__ float normL, normH;
  __shared__ float bces[2 * NSEL];

  const int tid = threadIdx.x;
  const int r = blockIdx.x;
  const int rbase = r * C;

  if (tid < 2) { posCnt[tid] = 0; candCnt[tid] = 0; }
  __syncthreads();

  // ---- Phase A: stream labels, 8-wide hash, compact above-TH comps ----
  const int4* labL4 = reinterpret_cast<const int4*>(lab + (size_t)rbase);
  const int4* labH4 = reinterpret_cast<const int4*>(lab + ((size_t)r + HALF) * C);

#define CAP(V, S, CQ) \
  if (V.x | V.y | V.z | V.w) { \
    if (V.x) { int s = atomicAdd(&posCnt[S], 1); if (s < 4) posBuf[S][s] = (CQ); }     \
    if (V.y) { int s = atomicAdd(&posCnt[S], 1); if (s < 4) posBuf[S][s] = (CQ) + 1; } \
    if (V.z) { int s = atomicAdd(&posCnt[S], 1); if (s < 4) posBuf[S][s] = (CQ) + 2; } \
    if (V.w) { int s = atomicAdd(&posCnt[S], 1); if (s < 4) posBuf[S][s] = (CQ) + 3; } \
  }

  // wave-aggregated LDS append (rare: P(lane) = 1/128)
#define APPEND(o, S, KA) \
  if ((o) >= TH) { \
    const uint32_t comp_ = (((o) & 0xFFFFFE00u) << 5) + (KA); \
    const uint64_t msk_ = __ballot(1); \
    const int pfx_ = mbcnt64(msk_); \
    int bse_ = 0; \
    if (pfx_ == 0) bse_ = atomicAdd(&candCnt[S], (int)__popcll(msk_)); \
    bse_ = __builtin_amdgcn_readfirstlane(bse_); \
    const int ix_ = bse_ + pfx_; \
    if (ix_ < CAPN) candArr[S][ix_] = comp_; \
  }

#pragma unroll 1
  for (int j = 0; j < QPT1; j += 2) {
    const int4 vL0 = labL4[j * T1 + tid];
    const int4 vL1 = labL4[(j + 1) * T1 + tid];
    const int4 vH0 = labH4[j * T1 + tid];
    const int4 vH1 = labH4[(j + 1) * T1 + tid];
    const int cq0 = (j * T1 + tid) << 2;          // quad j; quad j+1 at +2048
    uint32_t oa[8], ob[8];
    tf8((uint32_t)(rbase + cq0), (uint32_t)(rbase + cq0 + 2048), oa, ob);
    const uint32_t ka0 = (32767u + 0x40000000u) - (uint32_t)cq0;  // KeAdj
    const uint32_t ka1 = ka0 - 2048u;
#pragma unroll
    for (int k = 0; k < 4; ++k) {
      APPEND(oa[k],     0, ka0 - (uint32_t)k)
      APPEND(oa[4 + k], 0, ka1 - (uint32_t)k)
      APPEND(ob[k],     1, ka0 - (uint32_t)k)
      APPEND(ob[4 + k], 1, ka1 - (uint32_t)k)
    }
    CAP(vL0, 0, cq0) CAP(vL1, 0, cq0 + 2048)
    CAP(vH0, 1, cq0) CAP(vH1, 1, cq0 + 2048)
  }
#undef CAP
#undef APPEND

  __syncthreads();
  if (tid < 2) {   // sort 4 positive cols ascending (jax top_k tie order)
    int a = posBuf[tid][0], b2 = posBuf[tid][1], c2 = posBuf[tid][2], d = posBuf[tid][3];
#define CSW(x, y) if (x > y) { int t_ = x; x = y; y = t_; }
    CSW(a, b2) CSW(c2, d) CSW(a, c2) CSW(b2, d) CSW(b2, c2)
#undef CSW
    int* s = tid ? selH : selL;
    s[0] = a; s[1] = b2; s[2] = c2; s[3] = d;
  }
  __syncthreads();

  // ---- Phase B: waves 0/1 do exact top-20-set selection (radix descent);
  //      waves 2/3 load + normalize the two feature rows ----
  const int wv = tid >> 6;
  const int lane = tid & 63;
  if (wv < 2) {
    int* selX = wv ? selH : selL;
    const uint32_t* ca = candArr[wv];
    int n = candCnt[wv]; n = n < CAPN ? n : CAPN;
    const uint32_t ex0 = 16383u - (uint32_t)selX[0];
    const uint32_t ex1 = 16383u - (uint32_t)selX[1];
    const uint32_t ex2 = 16383u - (uint32_t)selX[2];
    const uint32_t ex3 = 16383u - (uint32_t)selX[3];
    uint32_t v0 = (lane       < n) ? ca[lane]       : 0u;
    uint32_t v1 = (lane + 64  < n) ? ca[lane + 64]  : 0u;
    uint32_t v2 = (lane + 128 < n) ? ca[lane + 128] : 0u;
    uint32_t v3 = (lane + 192 < n) ? ca[lane + 192] : 0u;
    // exclude positives by column match
#define EXCL(v) { const uint32_t a_ = (v) & 0x3FFFu; \
    if (a_ == ex0 || a_ == ex1 || a_ == ex2 || a_ == ex3) (v) = 0u; }
    EXCL(v0) EXCL(v1) EXCL(v2) EXCL(v3)
#undef EXCL
    // MSB radix descent: t_final = exact 20th-largest comp (values distinct)
    uint32_t t = 0;
#pragma unroll 1
    for (int b = 30; b >= 0; --b) {
      const uint32_t t2 = t | (1u << b);
      const int cnt = (int)__popcll(__ballot(v0 >= t2))
                    + (int)__popcll(__ballot(v1 >= t2))
                    + (int)__popcll(__ballot(v2 >= t2))
                    + (int)__popcll(__ballot(v3 >= t2));
      if (cnt >= NNEG) t = t2;
    }
    // emit the set {comp >= t} (exactly 20), mbcnt-prefix per slot
    int bse = NPOS;
    { const uint64_t m = __ballot(v0 >= t);
      if (v0 >= t) selX[bse + mbcnt64(m)] = 16383 - (int)(v0 & 0x3FFFu);
      bse += (int)__popcll(m); }
    { const uint64_t m = __ballot(v1 >= t);
      if (v1 >= t) selX[bse + mbcnt64(m)] = 16383 - (int)(v1 & 0x3FFFu);
      bse += (int)__popcll(m); }
    { const uint64_t m = __ballot(v2 >= t);
      if (v2 >= t) selX[bse + mbcnt64(m)] = 16383 - (int)(v2 & 0x3FFFu);
      bse += (int)__popcll(m); }
    { const uint64_t m = __ballot(v3 >= t);
      if (v3 >= t) selX[bse + mbcnt64(m)] = 16383 - (int)(v3 & 0x3FFFu);
      bse += (int)__popcll(m); }
    // canonicalize order (ascending col) -> deterministic across runs
    const int cmine = (lane < NNEG) ? selX[NPOS + lane] : 0x7FFFFFFF;
    int rank = 0;
#pragma unroll 1
    for (int jj = 0; jj < NNEG; ++jj) {
      const int cj = __shfl(cmine, jj, 64);
      rank += (cj < cmine) ? 1 : 0;
    }
    if (lane < NNEG) selX[NPOS + rank] = cmine;
  } else if (wv == 2) {
    const float a = feat[(size_t)r * D + lane];
    const float b = feat[(size_t)r * D + 64 + lane];
    ffL[lane] = a; ffL[64 + lane] = b;
    float s = a * a + b * b;
#pragma unroll
    for (int o = 32; o; o >>= 1) s += __shfl_xor(s, o, 64);
    if (lane == 0) normL = s;
  } else if (wv == 3) {
    const float a = feat[((size_t)r + HALF) * D + lane];
    const float b = feat[((size_t)r + HALF) * D + 64 + lane];
    ffH[lane] = a; ffH[64 + lane] = b;
    float s = a * a + b * b;
#pragma unroll
    for (int o = 32; o; o >>= 1) s += __shfl_xor(s, o, 64);
    if (lane == 0) normH = s;
  }
  __syncthreads();

  // ---- Phase C: 48 selected columns x 4 lanes each -> sim + BCE ----
  if (tid < 4 * 2 * NSEL) {
    const int ci = tid >> 2;            // 0..47
    const int k  = tid & 3;
    const bool isH = ci >= NSEL;
    const int g = isH ? ci - NSEL : ci;
    const int c = isH ? selH[g] : selL[g];
    const float* ff = isH ? ffH : ffL;
    const float4* pc = reinterpret_cast<const float4*>(proto + (size_t)c * D);
    float fp = 0.f, pp = 0.f;
#pragma unroll
    for (int qq = 0; qq < 8; ++qq) {
      const float4 pv = pc[k * 8 + qq];
      const int d0 = k * 32 + qq * 4;
      fp += ff[d0] * pv.x + ff[d0 + 1] * pv.y + ff[d0 + 2] * pv.z + ff[d0 + 3] * pv.w;
      pp += pv.x * pv.x + pv.y * pv.y + pv.z * pv.z + pv.w * pv.w;
    }
    fp += __shfl_xor(fp, 1, 64); pp += __shfl_xor(pp, 1, 64);
    fp += __shfl_xor(fp, 2, 64); pp += __shfl_xor(pp, 2, 64);
    if (k == 0) {
      const float x = (isH ? normH : normL) * pp;
      float rn = rsqrtf(x);
      rn = rn * (1.5f - 0.5f * x * rn * rn);   // 1 NR step for accuracy
      const float l = fp * rn * 10.0f;          // /TEMP, TEMP=0.1
      const float tgt = (g < NPOS) ? 0.25f : 0.0f;
      bces[ci] = fmaxf(l, 0.f) - l * tgt + __logf(1.0f + __expf(-fabsf(l)));
    }
  }
  __syncthreads();
  if (tid < 2) {
    float s = 0.f;
    const int base = tid * NSEL;
#pragma unroll
    for (int i = 0; i < NSEL; ++i) s += bces[base + i];
    row_ws[tid ? (r + HALF) : r] = s * (1.0f / NSEL);
  }
}

__global__ __launch_bounds__(T2) void supcon_reduce(
    const float* __restrict__ ws, float* __restrict__ out) {
  __shared__ float red[T2];
  const int tid = threadIdx.x;
  float s = 0.f;
#pragma unroll
  for (int j = 0; j < BS / T2; ++j) s += ws[j * T2 + tid];
  red[tid] = s;
  __syncthreads();
  for (int o = T2 / 2; o > 0; o >>= 1) {
    if (tid < o) red[tid] += red[tid + o];
    __syncthreads();
  }
  if (tid == 0) out[0] = red[0] * (1.0f / BS);
}

extern "C" void kernel_launch(void* const* d_in, const int* in_sizes, int n_in,
                              void* d_out, int out_size, void* d_ws, size_t ws_size,
                              hipStream_t stream) {
  (void)in_sizes; (void)n_in; (void)out_size; (void)ws_size;
  const float* feat  = (const float*)d_in[0];
  const float* proto = (const float*)d_in[1];
  const int*   lab   = (const int*)d_in[2];
  float* out = (float*)d_out;
  float* ws  = (float*)d_ws;   // [0..4095]: per-row mean-BCE

  supcon_fused<<<dim3(HALF), dim3(T1), 0, stream>>>(feat, proto, lab, ws);
  supcon_reduce<<<dim3(1), dim3(T2), 0, stream>>>(ws, out);
}